// Round 3
// baseline (2218.375 us; speedup 1.0000x reference)
//
#include <hip/hip_runtime.h>
#include <math.h>

// Problem constants
#define Bc 2
#define Lc 2048
#define Dc 4096
#define DZc 1024
#define Hc 16
#define HDc 64

// Output layout (flat float32, in reference return order)
#define OFF_Z     16777216L    // (2,2048,4096)
#define OFF_KR    20971520L    // (2,2048,1024)
#define OFF_ATTN  25165824L    // (2,16,2048,2048)
#define OFF_SC    159383552L   // (2,16,2048,2048)

typedef __bf16 bf16x8 __attribute__((ext_vector_type(8)));
typedef unsigned short us8 __attribute__((ext_vector_type(8)));
typedef float f32x4 __attribute__((ext_vector_type(4)));

// Split fp32 -> bf16 hi (truncate) + bf16 lo (truncated exact residual).
__device__ __forceinline__ void split1(float v, unsigned short& h, unsigned short& l)
{
    unsigned u = __float_as_uint(v);
    h = (unsigned short)(u >> 16);
    float r = v - __uint_as_float(u & 0xFFFF0000u);
    l = (unsigned short)(__float_as_uint(r) >> 16);
}

__device__ __forceinline__ void split8(const float* f, us8& hi, us8& lo)
{
#pragma unroll
    for (int j = 0; j < 8; ++j) {
        unsigned short h, l;
        split1(f[j], h, l);
        hi[j] = h; lo[j] = l;
    }
}

// async global->LDS, 16B per lane (global_load_lds_dwordx4).
__device__ __forceinline__ void gload16(const unsigned short* g, unsigned short* l)
{
    __builtin_amdgcn_global_load_lds(
        (const __attribute__((address_space(1))) void*)g,
        (__attribute__((address_space(3))) void*)l, 16, 0, 0);
}

// ===========================================================================
// gemm8: 256x256-tile, 8-wave, phase-interleaved hi/lo split-precision GEMM.
// B pre-transposed to [N][K]. C = scale*(A@B^T) (+bias). Batch via flat
// strides (bz * sA2/sB2/sC2). Up to 3 N-segments (seg = n>>segshift), each
// with its own fp32 / bf16-pair sinks (all sharing the batch stride sC2,
// interpreted in each sink's own element units).
// Schedule per K-step (BK=32, dbuf): phase0 issues all 8 prefetches + reads
// B frags + A quad0; phases 1-3 read A quads; each phase: s_barrier ->
// MFMA cluster (setprio) -> s_barrier; step ends with __syncthreads()
// (the single vmcnt drain; prefetches had ~4 phases to complete).
// LDS 128 KiB -> 1 block/CU. Addressing identical to the verified r2 kernel.
// ===========================================================================
template<int NPROD>
__global__ __launch_bounds__(512, 2) void gemm8(
    const unsigned short* __restrict__ Ahi, const unsigned short* __restrict__ Alo,
    const unsigned short* __restrict__ Bhi, const unsigned short* __restrict__ Blo,
    float* __restrict__ Cf0, unsigned short* __restrict__ Chi0, unsigned short* __restrict__ Clo0,
    const float* __restrict__ bias0, int ldc0,
    float* __restrict__ Cf1, unsigned short* __restrict__ Chi1, unsigned short* __restrict__ Clo1,
    const float* __restrict__ bias1, int ldc1,
    float* __restrict__ Cf2, unsigned short* __restrict__ Chi2, unsigned short* __restrict__ Clo2,
    const float* __restrict__ bias2, int ldc2,
    int K, int lda, int ldb,
    long sA2, long sB2, long sC2, float scale, int segshift)
{
    __shared__ __align__(16) unsigned short sm[2][4][8192]; // [dbuf][Ahi,Alo,Bhi,Blo]

    // bijective XCD swizzle (m204) over the (x,y) plane
    const int gx = gridDim.x;
    const int nwg = gx * gridDim.y;
    {
    }
    int orig = blockIdx.y * gx + blockIdx.x;
    int qq = nwg >> 3, rr = nwg & 7;
    int xcd = orig & 7, lid = orig >> 3;
    int wg = (xcd < rr ? xcd * (qq + 1) : rr * (qq + 1) + (xcd - rr) * qq) + lid;
    const int m0 = (wg / gx) * 256;
    const int n0 = (wg % gx) * 256;

    const long abz = (long)blockIdx.z * sA2;
    const long bbz = (long)blockIdx.z * sB2;
    const long cbz = (long)blockIdx.z * sC2;

    const int t = threadIdx.x, w = t >> 6, l = t & 63;
    const int lr = l & 15, lk = l >> 4;
    const int wm0 = (w >> 2) * 128, wn0 = (w & 3) * 64;

    // staging: wave w stages chunks j = w*2+{0,1}; chunk j = 16 rows.
    // slot-XOR pre-swizzle on the GLOBAL source (linear LDS dest).
    const int jch = w * 2;
    long offA[2], offB[2];
#pragma unroll
    for (int jj = 0; jj < 2; ++jj) {
        int j = jch + jj;
        int r = j * 16 + (l >> 2);
        int ks = (l & 3) ^ (r & 3);
        offA[jj] = abz + (long)(m0 + r) * lda + ks * 8;
        offB[jj] = bbz + (long)(n0 + r) * ldb + ks * 8;
    }

    // frag read offsets (ushort units), same XOR on the read side
    const int rs = lk ^ (lr & 3);
    int aoff[8], boff[4];
#pragma unroll
    for (int i = 0; i < 8; ++i) aoff[i] = (wm0 + i * 16 + lr) * 32 + rs * 8;
#pragma unroll
    for (int j = 0; j < 4; ++j) boff[j] = (wn0 + j * 16 + lr) * 32 + rs * 8;

    f32x4 acc[8][4] = {};

    const int nt = K / 32;
    // prologue: stage K-step 0 into buf 0
#pragma unroll
    for (int jj = 0; jj < 2; ++jj) {
        int j = jch + jj;
        gload16(Ahi + offA[jj], &sm[0][0][j * 512]);
        gload16(Alo + offA[jj], &sm[0][1][j * 512]);
        gload16(Bhi + offB[jj], &sm[0][2][j * 512]);
        gload16(Blo + offB[jj], &sm[0][3][j * 512]);
    }
    __syncthreads();   // full drain: buf0 complete for all waves

    for (int tI = 0; tI < nt; ++tI) {
        const int cur = tI & 1, nxt = cur ^ 1;

        // ---- phase 0: issue ALL prefetches, read B frags + A quad 0 ----
        if (tI + 1 < nt) {
            const long ko = (long)(tI + 1) * 32;
#pragma unroll
            for (int jj = 0; jj < 2; ++jj) {
                int j = jch + jj;
                gload16(Ahi + offA[jj] + ko, &sm[nxt][0][j * 512]);
                gload16(Alo + offA[jj] + ko, &sm[nxt][1][j * 512]);
                gload16(Bhi + offB[jj] + ko, &sm[nxt][2][j * 512]);
                gload16(Blo + offB[jj] + ko, &sm[nxt][3][j * 512]);
            }
        }
        us8 bh[4], bl[4];
#pragma unroll
        for (int j = 0; j < 4; ++j) {
            bh[j] = *(const us8*)&sm[cur][2][boff[j]];
            bl[j] = *(const us8*)&sm[cur][3][boff[j]];
        }
#pragma unroll
        for (int q = 0; q < 4; ++q) {
            us8 a0h = *(const us8*)&sm[cur][0][aoff[q * 2]];
            us8 a0l = *(const us8*)&sm[cur][1][aoff[q * 2]];
            us8 a1h = *(const us8*)&sm[cur][0][aoff[q * 2 + 1]];
            us8 a1l = *(const us8*)&sm[cur][1][aoff[q * 2 + 1]];
            __builtin_amdgcn_s_barrier();
            __builtin_amdgcn_sched_barrier(0);
            __builtin_amdgcn_s_setprio(1);
#pragma unroll
            for (int ii = 0; ii < 2; ++ii) {
                const int i = q * 2 + ii;
                bf16x8 xh = __builtin_bit_cast(bf16x8, ii ? a1h : a0h);
                bf16x8 xl = __builtin_bit_cast(bf16x8, ii ? a1l : a0l);
#pragma unroll
                for (int j = 0; j < 4; ++j) {
                    bf16x8 yh = __builtin_bit_cast(bf16x8, bh[j]);
                    bf16x8 yl = __builtin_bit_cast(bf16x8, bl[j]);
                    acc[i][j] = __builtin_amdgcn_mfma_f32_16x16x32_bf16(xh, yh, acc[i][j], 0, 0, 0);
                    acc[i][j] = __builtin_amdgcn_mfma_f32_16x16x32_bf16(xh, yl, acc[i][j], 0, 0, 0);
                    acc[i][j] = __builtin_amdgcn_mfma_f32_16x16x32_bf16(xl, yh, acc[i][j], 0, 0, 0);
                    if constexpr (NPROD == 4)
                        acc[i][j] = __builtin_amdgcn_mfma_f32_16x16x32_bf16(xl, yl, acc[i][j], 0, 0, 0);
                }
            }
            __builtin_amdgcn_s_setprio(0);
            __builtin_amdgcn_sched_barrier(0);
            if (q < 3) __builtin_amdgcn_s_barrier();
        }
        __syncthreads();   // single vmcnt drain per K-step (prefetch complete)
    }

    // Epilogue. C/D layout: col = lane&15, row = (lane>>4)*4 + reg.
    const int nA = n0 + wn0;
    const int seg = nA >> segshift;
    float* Cf; unsigned short* Chi; unsigned short* Clo; const float* bias; int ldc;
    if (seg == 0)      { Cf = Cf0; Chi = Chi0; Clo = Clo0; bias = bias0; ldc = ldc0; }
    else if (seg == 1) { Cf = Cf1; Chi = Chi1; Clo = Clo1; bias = bias1; ldc = ldc1; }
    else               { Cf = Cf2; Chi = Chi2; Clo = Clo2; bias = bias2; ldc = ldc2; }
    const int ncol0 = nA - (seg << segshift);
#pragma unroll
    for (int i = 0; i < 8; ++i) {
        const int mrow = m0 + wm0 + i * 16 + lk * 4;
#pragma unroll
        for (int j = 0; j < 4; ++j) {
            const int nc = ncol0 + j * 16 + lr;
            const float bv = bias ? bias[nc] : 0.0f;
#pragma unroll
            for (int r = 0; r < 4; ++r) {
                float v = acc[i][j][r] * scale + bv;
                long co = cbz + (long)(mrow + r) * ldc + nc;
                if (Cf) Cf[co] = v;
                if (Chi) { unsigned short hh, ll; split1(v, hh, ll); Chi[co] = hh; Clo[co] = ll; }
            }
        }
    }
}

// ===========================================================================
// gemm_hl: verified 128x128 hi/lo kernel (r2), kept for steps 10 & 12.
// Added: trik (truncate K at m0+BM) + corr (suffix-V mask correction).
// ===========================================================================
template<int BN, int NPROD, int AMODE>
__global__ __launch_bounds__(256, 2) void gemm_hl(
    const unsigned short* __restrict__ Ahi, const unsigned short* __restrict__ Alo,
    const float* __restrict__ Af,
    const unsigned short* __restrict__ Bhi, const unsigned short* __restrict__ Blo,
    float* __restrict__ Cf0, unsigned short* __restrict__ Chi0, unsigned short* __restrict__ Clo0,
    const float* __restrict__ bias0, int ldc0,
    float* __restrict__ Cf1, unsigned short* __restrict__ Chi1, unsigned short* __restrict__ Clo1,
    const float* __restrict__ bias1, int ldc1,
    float* __restrict__ Cf2, unsigned short* __restrict__ Chi2, unsigned short* __restrict__ Clo2,
    const float* __restrict__ bias2, int ldc2,
    int M, int N, int K, int lda, int ldb,
    long sA1, long sA2, long sB1, long sB2, long sC1, long sC2,
    int Hdiv, int causal, float scale, float maskval, int segshift,
    int trik, const float* __restrict__ corr)
{
    constexpr int BM = 128, BK = 32;
    constexpr int MR = (BN == 128) ? 4 : 2;
    constexpr int NR = 4;
    constexpr int AISS = 2;
    constexpr int BISS = (BN == 128) ? 2 : 1;

    __shared__ __align__(16) unsigned short sA[2][BM * BK];
    __shared__ __align__(16) unsigned short sB[2][BN * BK];

    const int bz = blockIdx.z;
    const long abase = (long)(bz / Hdiv) * sA1 + (long)(bz % Hdiv) * sA2;
    const long bbase = (long)(bz / Hdiv) * sB1 + (long)(bz % Hdiv) * sB2;
    const long cbase = (long)(bz / Hdiv) * sC1 + (long)(bz % Hdiv) * sC2;

    const int m0 = blockIdx.y * BM;
    const int n0 = blockIdx.x * BN;
    const int t  = threadIdx.x;

    const int seg = n0 >> segshift;
    float* Cf; unsigned short* Chi; unsigned short* Clo; const float* bias; int ldc;
    if (seg == 0)      { Cf = Cf0; Chi = Chi0; Clo = Clo0; bias = bias0; ldc = ldc0; }
    else if (seg == 1) { Cf = Cf1; Chi = Chi1; Clo = Clo1; bias = bias1; ldc = ldc1; }
    else               { Cf = Cf2; Chi = Chi2; Clo = Clo2; bias = bias2; ldc = ldc2; }
    const int ncol0 = n0 - (seg << segshift);

    if (causal && n0 > m0 + BM - 1) {
        unsigned short mh, ml; split1(maskval, mh, ml);
        for (int e = 0; e < BM * BN / 256; ++e) {
            int i = e * 256 + t;
            int r = i / BN, c = i % BN;
            long co = cbase + (long)(m0 + r) * ldc + (ncol0 + c);
            if (Cf)  Cf[co] = maskval;
            if (Chi) { Chi[co] = mh; Clo[co] = ml; }
        }
        return;
    }

    const int w  = t >> 6, l = t & 63;
    const int lr = l & 15, lk = l >> 4;
    const int wm0 = (BN == 128) ? (w >> 1) * 64 : w * 32;
    const int wn0 = (BN == 128) ? (w & 1) * 64 : 0;

    long offA[AISS]; long offB[BISS];
    const float* gA[2];
    if constexpr (AMODE == 0) {
#pragma unroll
        for (int jj = 0; jj < AISS; ++jj) {
            int j = w * AISS + jj;
            int r = j * 16 + (l >> 2);
            int ks = (l & 3) ^ (r & 3);
            offA[jj] = abase + (long)(m0 + r) * lda + ks * 8;
        }
    } else {
#pragma unroll
        for (int e = 0; e < 2; ++e) {
            int s = e * 256 + t;
            int r = s >> 2, ks = s & 3;
            gA[e] = Af + abase + (long)(m0 + r) * lda + ks * 8;
        }
    }
#pragma unroll
    for (int jj = 0; jj < BISS; ++jj) {
        int j = w * BISS + jj;
        int r = j * 16 + (l >> 2);
        int ks = (l & 3) ^ (r & 3);
        offB[jj] = bbase + (long)(n0 + r) * ldb + ks * 8;
    }

    const int rs = lk ^ (lr & 3);
    int aoff[MR], boff[NR];
#pragma unroll
    for (int i = 0; i < MR; ++i) aoff[i] = (wm0 + i * 16 + lr) * 32 + rs * 8;
#pragma unroll
    for (int j = 0; j < NR; ++j) boff[j] = (wn0 + j * 16 + lr) * 32 + rs * 8;

    f32x4 acc[MR][NR] = {};

    const int Kend = trik ? ((m0 + BM < K) ? (m0 + BM) : K) : K;

    for (int k0 = 0; k0 < Kend; k0 += BK) {
        if constexpr (AMODE == 0) {
#pragma unroll
            for (int jj = 0; jj < AISS; ++jj) {
                int j = w * AISS + jj;
                gload16(Ahi + offA[jj] + k0, &sA[0][j * 512]);
                gload16(Alo + offA[jj] + k0, &sA[1][j * 512]);
            }
        } else {
#pragma unroll
            for (int e = 0; e < 2; ++e) {
                int s = e * 256 + t;
                int r = s >> 2, ks = s & 3;
                const float* p = gA[e] + k0;
                float f[8];
                *(float4*)&f[0] = *(const float4*)p;
                *(float4*)&f[4] = *(const float4*)(p + 4);
                us8 hi, lo; split8(f, hi, lo);
                int q = r * 32 + (ks ^ (r & 3)) * 8;
                *(us8*)&sA[0][q] = hi;
                *(us8*)&sA[1][q] = lo;
            }
        }
#pragma unroll
        for (int jj = 0; jj < BISS; ++jj) {
            int j = w * BISS + jj;
            gload16(Bhi + offB[jj] + k0, &sB[0][j * 512]);
            gload16(Blo + offB[jj] + k0, &sB[1][j * 512]);
        }
        __syncthreads();

        us8 ah[MR], al[MR], bh[NR], bl[NR];
#pragma unroll
        for (int i = 0; i < MR; ++i) {
            ah[i] = *(const us8*)&sA[0][aoff[i]];
            al[i] = *(const us8*)&sA[1][aoff[i]];
        }
#pragma unroll
        for (int j = 0; j < NR; ++j) {
            bh[j] = *(const us8*)&sB[0][boff[j]];
            bl[j] = *(const us8*)&sB[1][boff[j]];
        }
#pragma unroll
        for (int i = 0; i < MR; ++i) {
            bf16x8 xh = __builtin_bit_cast(bf16x8, ah[i]);
            bf16x8 xl = __builtin_bit_cast(bf16x8, al[i]);
#pragma unroll
            for (int j = 0; j < NR; ++j) {
                bf16x8 yh = __builtin_bit_cast(bf16x8, bh[j]);
                bf16x8 yl = __builtin_bit_cast(bf16x8, bl[j]);
                acc[i][j] = __builtin_amdgcn_mfma_f32_16x16x32_bf16(xh, yh, acc[i][j], 0, 0, 0);
                acc[i][j] = __builtin_amdgcn_mfma_f32_16x16x32_bf16(xh, yl, acc[i][j], 0, 0, 0);
                acc[i][j] = __builtin_amdgcn_mfma_f32_16x16x32_bf16(xl, yh, acc[i][j], 0, 0, 0);
                if constexpr (NPROD == 4)
                    acc[i][j] = __builtin_amdgcn_mfma_f32_16x16x32_bf16(xl, yl, acc[i][j], 0, 0, 0);
            }
        }
        __syncthreads();
    }

#pragma unroll
    for (int i = 0; i < MR; ++i) {
        const int mrow = m0 + wm0 + i * 16 + lk * 4;
#pragma unroll
        for (int j = 0; j < NR; ++j) {
            const int n  = wn0 + j * 16 + lr;
            const int nc = ncol0 + n;
            const float bv = bias ? bias[nc] : 0.0f;
            float cv = 0.0f;
            if (corr)
                cv = maskval * corr[((long)(bz / Hdiv) * 17 + ((m0 >> 7) + 1)) * 1024
                                    + (long)(bz % Hdiv) * 64 + nc];
#pragma unroll
            for (int r = 0; r < 4; ++r) {
                float v = acc[i][j][r] * scale + bv + cv;
                if (causal && (n0 + n) > mrow + r) v = maskval;
                long co = cbase + (long)(mrow + r) * ldc + nc;
                if (Cf) Cf[co] = v;
                if (Chi) { unsigned short hh, ll; split1(v, hh, ll); Chi[co] = hh; Clo[co] = ll; }
            }
        }
    }
}

// fp32 [n] -> bf16 hi/lo, 8 elems/thread, coalesced.
__global__ __launch_bounds__(256) void split_kernel(
    const float* __restrict__ in, unsigned short* __restrict__ ohi,
    unsigned short* __restrict__ olo, long n8)
{
    long t = (long)blockIdx.x * 256 + threadIdx.x;
    if (t >= n8) return;
    const float* p = in + t * 8;
    float f[8];
    *(float4*)&f[0] = *(const float4*)p;
    *(float4*)&f[4] = *(const float4*)(p + 4);
    us8 hi, lo; split8(f, hi, lo);
    *(us8*)&ohi[t * 8] = hi;
    *(us8*)&olo[t * 8] = lo;
}

// in [K][N] fp32 (batched) -> out [N][K] bf16 hi/lo. 64x64 LDS tile.
__global__ __launch_bounds__(256) void tsp_kernel(
    const float* __restrict__ in, unsigned short* __restrict__ ohi,
    unsigned short* __restrict__ olo, int K, int N, long ibs, long obs)
{
    __shared__ float tile[64][65];
    int k0 = blockIdx.x * 64, n0 = blockIdx.y * 64;
    const float* ib = in + (long)blockIdx.z * ibs;
    ohi += (long)blockIdx.z * obs;
    olo += (long)blockIdx.z * obs;
    int t = threadIdx.x;
#pragma unroll
    for (int e = 0; e < 16; ++e) {
        int i = e * 256 + t; int r = i >> 6, c = i & 63;
        tile[r][c] = ib[(long)(k0 + r) * N + (n0 + c)];
    }
    __syncthreads();
#pragma unroll
    for (int e = 0; e < 16; ++e) {
        int i = e * 256 + t; int r = i >> 6, c = i & 63;
        unsigned short h, l; split1(tile[c][r], h, l);
        long o = (long)(n0 + r) * K + (k0 + c);
        ohi[o] = h; olo[o] = l;
    }
}

// RoPE over (B,L,H,64) fp32 [4096][1024] -> bf16 hi/lo (+ optional fp32 sink).
__global__ __launch_bounds__(256) void rope_split_kernel(
    const float* __restrict__ in,
    unsigned short* __restrict__ dhi, unsigned short* __restrict__ dlo, int dld,
    float* __restrict__ f32out, int fld)
{
    int t = blockIdx.x * 256 + threadIdx.x;
    int i = t & 31;
    int h = (t >> 5) & 15;
    int l = (t >> 9) & 2047;
    int b = t >> 20;
    long row = (long)b * Lc + l;

    float inv_freq = powf(10000.0f, -(float)i * (1.0f / 32.0f));
    float ang = (float)l * inv_freq;
    float s, c;
    sincosf(ang, &s, &c);

    long ia = row * 1024 + h * 64 + i;
    float x1 = in[ia], x2 = in[ia + 32];
    float o1 = x1 * c - x2 * s;
    float o2 = x2 * c + x1 * s;
    long oa = row * dld + h * 64 + i;
    unsigned short h1, l1, h2, l2;
    split1(o1, h1, l1); split1(o2, h2, l2);
    dhi[oa] = h1; dlo[oa] = l1;
    dhi[oa + 32] = h2; dlo[oa + 32] = l2;
    if (f32out) {
        long fa = row * fld + h * 64 + i;
        f32out[fa] = o1; f32out[fa + 32] = o2;
    }
}

// Row softmax over 2048-wide rows. One block (256 threads) per row.
__global__ __launch_bounds__(256) void softmax_kernel(
    const float* __restrict__ S, float* __restrict__ P)
{
    long row = blockIdx.x;
    const float* sr = S + row * Lc;
    float* pr = P + row * Lc;
    int t = threadIdx.x;

    float v[8];
    float m = -3.4e38f;
#pragma unroll
    for (int e = 0; e < 8; ++e) { v[e] = sr[t + e * 256]; m = fmaxf(m, v[e]); }
#pragma unroll
    for (int off = 32; off >= 1; off >>= 1) m = fmaxf(m, __shfl_xor(m, off));
    __shared__ float redm[4], reds[4];
    int wave = t >> 6;
    if ((t & 63) == 0) redm[wave] = m;
    __syncthreads();
    m = fmaxf(fmaxf(redm[0], redm[1]), fmaxf(redm[2], redm[3]));

    float s = 0.0f;
#pragma unroll
    for (int e = 0; e < 8; ++e) { v[e] = __expf(v[e] - m); s += v[e]; }
#pragma unroll
    for (int off = 32; off >= 1; off >>= 1) s += __shfl_xor(s, off);
    if ((t & 63) == 0) reds[wave] = s;
    __syncthreads();
    s = reds[0] + reds[1] + reds[2] + reds[3];
    float inv = 1.0f / s;
#pragma unroll
    for (int e = 0; e < 8; ++e) pr[t + e * 256] = v[e] * inv;
}

// part[b][j][c] = sum_{kk<128} V[b][128j+kk][c]   (V = value fp32 [2][2048][1024])
__global__ __launch_bounds__(256) void sufpart_kernel(
    const float* __restrict__ V, float* __restrict__ part)
{
    int j = blockIdx.x, b = blockIdx.y, t = threadIdx.x;
#pragma unroll
    for (int e = 0; e < 4; ++e) {
        int c = t + e * 256;
        float a = 0.0f;
        for (int kk = 0; kk < 128; ++kk)
            a += V[((long)b * 2048 + j * 128 + kk) * 1024 + c];
        part[((long)b * 16 + j) * 1024 + c] = a;
    }
}

// suf[b][j][c] = sum_{j'>=j} part[b][j'][c]  for j=1..15; suf[b][16][c]=0.
__global__ __launch_bounds__(256) void sufacc_kernel(
    const float* __restrict__ part, float* __restrict__ suf)
{
    int g = blockIdx.x * 256 + threadIdx.x;  // 2048
    int b = g >> 10, c = g & 1023;
    float a = 0.0f;
    suf[((long)b * 17 + 16) * 1024 + c] = 0.0f;
    for (int j = 15; j >= 1; --j) {
        a += part[((long)b * 16 + j) * 1024 + c];
        suf[((long)b * 17 + j) * 1024 + c] = a;
    }
}

extern "C" void kernel_launch(void* const* d_in, const int* in_sizes, int n_in,
                              void* d_out, int out_size, void* d_ws, size_t ws_size,
                              hipStream_t stream)
{
    const float* x        = (const float*)d_in[0];
    const float* W_latent = (const float*)d_in[1];
    const float* W_q_down = (const float*)d_in[2];
    const float* b_q_down = (const float*)d_in[3];
    const float* W_q_up   = (const float*)d_in[4];
    const float* W_k_up   = (const float*)d_in[5];
    const float* W_v_up   = (const float*)d_in[6];
    const float* W_x_rope = (const float*)d_in[7];
    const float* W_k_rope = (const float*)d_in[8];
    const float* W_o      = (const float*)d_in[9];

    float* out      = (float*)d_out;
    float* z_out    = out + OFF_Z;
    float* kr_out   = out + OFF_KR;
    float* attn_out = out + OFF_ATTN;
    float* sc_out   = out + OFF_SC;

    // --- scratch carved from the attn output region (dead until softmax) ---
    char* scr = (char*)attn_out;
    unsigned short* xhi  = (unsigned short*)scr;        // us offsets below
    unsigned short* xlo  = xhi + 16777216;
    unsigned short* qlhi = xhi + 33554432;              // qlhi -> zhi stride 8388608
    unsigned short* qllo = xhi + 37748736;
    unsigned short* zhi  = xhi + 41943040;
    unsigned short* zlo  = xhi + 46137344;
    unsigned short* qchi = xhi + 50331648;              // qchi -> kchi stride 16777216
    unsigned short* qclo = xhi + 58720256;
    unsigned short* kchi = xhi + 67108864;
    unsigned short* kclo = xhi + 75497472;
    float* T2 = (float*)(scr + 167772160);              // T2 -> T stride 16777216 floats
    float* T  = (float*)(scr + 234881024);
    // scratch ends at byte 251,658,240 < 536,870,912

    // --- d_ws (80 MB used) ---
    char* w8 = (char*)d_ws;
    unsigned short* Wf1hi = (unsigned short*)w8;        // [3072][4096] pair (dead after F123)
    unsigned short* Wf1lo = Wf1hi + 12582912;
    unsigned short* W78hi = Wf1hi + 25165824;           // [2048][1024]: [W_q_upT|W_x_ropeT]
    unsigned short* W78lo = Wf1hi + 27262976;
    unsigned short* W56hi = Wf1hi + 29360128;           // [2048][1024]: [W_k_upT|W_v_upT]
    unsigned short* W56lo = Wf1hi + 31457280;
    unsigned short* Wohi  = Wf1hi + 33554432;           // [4096][1024] pair
    unsigned short* Wolo  = Wf1hi + 37748736;
    unsigned short* vThi  = (unsigned short*)w8;        // reuse dead Wf123 region
    unsigned short* vTlo  = vThi + 4194304;
    unsigned short* hohi  = vThi + 8388608;
    unsigned short* holo  = vThi + 12582912;
    float* suf  = (float*)(w8 + 33554432);              // [2][17][1024]
    float* part = (float*)(w8 + 33693696);              // [2][16][1024]

    float* nf = nullptr; unsigned short* nus = nullptr; const float* ncf = nullptr;
    const unsigned short* nu = nullptr;

    // 0. x -> hi/lo pair
    split_kernel<<<dim3(8192), 256, 0, stream>>>(x, xhi, xlo, 2097152L);

    // transposed-split weights for fused {1,2,3}: [3072][4096]
    tsp_kernel<<<dim3(64, 16, 1), 256, 0, stream>>>(W_latent, Wf1hi,           Wf1lo,           4096, 1024, 0, 0);
    tsp_kernel<<<dim3(64, 16, 1), 256, 0, stream>>>(W_q_down, Wf1hi + 4194304, Wf1lo + 4194304, 4096, 1024, 0, 0);
    tsp_kernel<<<dim3(64, 16, 1), 256, 0, stream>>>(W_k_rope, Wf1hi + 8388608, Wf1lo + 8388608, 4096, 1024, 0, 0);

    // F123: [z | q_lat | kr_pre] = x @ [W_latent | W_q_down | W_k_rope]
    gemm8<3><<<dim3(12, 16, 1), 512, 0, stream>>>(
        xhi, xlo, Wf1hi, Wf1lo,
        z_out, zhi, zlo, ncf, 1024,
        nf, qlhi, qllo, b_q_down, 1024,
        T, nus, nus, ncf, 1024,
        4096, 4096, 4096, 0, 0, 0, 1.0f, 10);

    // rope(k): T -> kcat[1024:2048] pair + kr_out fp32
    rope_split_kernel<<<dim3(8192), 256, 0, stream>>>(T, kchi + 1024, kclo + 1024, 2048, kr_out, 1024);

    // weights for fused {5,6} and {7,8}
    tsp_kernel<<<dim3(16, 16, 1), 256, 0, stream>>>(W_q_up,   W78hi,           W78lo,           1024, 1024, 0, 0);
    tsp_kernel<<<dim3(16, 16, 1), 256, 0, stream>>>(W_x_rope, W78hi + 1048576, W78lo + 1048576, 1024, 1024, 0, 0);
    tsp_kernel<<<dim3(16, 16, 1), 256, 0, stream>>>(W_k_up,   W56hi,           W56lo,           1024, 1024, 0, 0);
    tsp_kernel<<<dim3(16, 16, 1), 256, 0, stream>>>(W_v_up,   W56hi + 1048576, W56lo + 1048576, 1024, 1024, 0, 0);

    // F56+F78 fused (batch=2): b0: q_lat @ [W_q_up|W_x_rope] -> {qcat[0:1024], T2}
    //                          b1: z     @ [W_k_up|W_v_up]   -> {kcat[0:1024], T }
    gemm8<3><<<dim3(8, 16, 2), 512, 0, stream>>>(
        qlhi, qllo, W78hi, W78lo,
        nf, qchi, qclo, ncf, 2048,
        T2, nus, nus, ncf, 1024,
        nf, nus, nus, ncf, 0,
        1024, 1024, 1024, 8388608L, 4194304L, 16777216L, 1.0f, 10);

    // rope(q): T2 -> qcat[1024:2048] pair
    rope_split_kernel<<<dim3(8192), 256, 0, stream>>>(T2, qchi + 1024, qclo + 1024, 2048, nullptr, 0);

    // valT: value (b,l,c) -> (b,c,l) bf16 pair
    tsp_kernel<<<dim3(32, 16, 2), 256, 0, stream>>>(T, vThi, vTlo, 2048, 1024, 2097152, 2097152);

    // suffix-V for the triangular step-12 correction
    sufpart_kernel<<<dim3(16, 2), 256, 0, stream>>>(T, part);
    sufacc_kernel<<<dim3(8), 256, 0, stream>>>(part, suf);

    // W_o^T pair
    tsp_kernel<<<dim3(16, 64, 1), 256, 0, stream>>>(W_o, Wohi, Wolo, 1024, 4096, 0, 0);

    // 10. scores = Q @ K^T / sqrt(128), causal -1e6
    gemm_hl<128, 3, 0><<<dim3(16, 16, 32), 256, 0, stream>>>(
        qchi, qclo, nullptr, kchi, kclo,
        sc_out, nus, nus, ncf, 2048,
        nf, nus, nus, ncf, 0,
        nf, nus, nus, ncf, 0,
        Lc, Lc, 128, 2048, 2048,
        4194304L, 128L, 4194304L, 128L, 67108864L, 4194304L,
        Hc, 1, 0.08838834764831845f, -1e6f, 20, 0, nullptr);

    // 11. attn_weights = softmax(scores)
    softmax_kernel<<<dim3(Bc * Hc * Lc), 256, 0, stream>>>(sc_out, attn_out);

    // 12. head_out = scores @ value, triangular-truncated + suffix correction
    gemm_hl<64, 4, 1><<<dim3(1, 16, 32), 256, 0, stream>>>(
        nu, nu, sc_out, vThi, vTlo,
        nf, hohi, holo, ncf, 1024,
        nf, nus, nus, ncf, 0,
        nf, nus, nus, ncf, 0,
        Lc, 64, Lc, 2048, 2048,
        67108864L, 4194304L, 2097152L, 131072L, 2097152L, 64L,
        Hc, 0, 1.0f, -1e6f, 20, 1, suf);

    // 13. out = head_out @ W_o
    gemm8<4><<<dim3(16, 16, 1), 512, 0, stream>>>(
        hohi, holo, Wohi, Wolo,
        out, nus, nus, ncf, 4096,
        nf, nus, nus, ncf, 0,
        nf, nus, nus, ncf, 0,
        1024, 1024, 1024, 0, 0, 0, 1.0f, 12);
}